// Round 1
// baseline (102.421 us; speedup 1.0000x reference)
//
#include <hip/hip_runtime.h>
#include <math.h>

// Problem constants (fixed by reference): B=256 batches, N=M=256 points, D=4.
#define BB 256
#define NN 256
#define MM 256

#define SENTINEL 3.0e38f

__global__ __launch_bounds__(256) void chamfer_split_kernel(
    const float* __restrict__ target,   // [B, N, 4]
    const float* __restrict__ reco,     // [B, M, 4]
    const int*   __restrict__ in_pid,   // [B, N]
    const int*   __restrict__ out_pid,  // [B, M]
    float* __restrict__ out)            // [2] accumulated means
{
    const int b = blockIdx.x;
    const int t = threadIdx.x;   // 0..255, owns row n=t (pass 1) and col m=t (pass 2)

    __shared__ float4 sT[NN];    // target points, 4 KB
    __shared__ float4 sR[MM];    // reco points, 4 KB
    __shared__ int    sMx[NN];   // mask_x
    __shared__ int    sMy[MM];   // mask_y
    __shared__ int    sNx, sNy;
    __shared__ float  wsum[4][4];  // per-wave partials: [wave][{sum_xy,sum_yx,sum_nx,sum_ny0}]

    // ---- stage batch b into LDS (fully coalesced float4 loads) ----
    const float4* tg = (const float4*)(target + (size_t)b * NN * 4);
    const float4* rc = (const float4*)(reco   + (size_t)b * MM * 4);
    float4 x = tg[t];
    float4 y = rc[t];
    sT[t] = x;
    sR[t] = y;
    const int mx = (in_pid[b * NN + t] != 0);
    const int my = (out_pid[b * MM + t] != 0);
    sMx[t] = mx;
    sMy[t] = my;
    if (t == 0) { sNx = 0; sNy = 0; }
    __syncthreads();

    // ---- counts via wave ballot (wave = 64 on gfx950) ----
    unsigned long long bx = __ballot(mx);
    unsigned long long by = __ballot(my);
    if ((t & 63) == 0) {
        atomicAdd(&sNx, (int)__popcll(bx));
        atomicAdd(&sNy, (int)__popcll(by));
    }
    __syncthreads();
    const int nx = sNx;
    const int ny = sNy;

    // ---- pass 1: thread t = row n; min over valid m of squared dist ----
    // all threads read the same sR[m]/sMy[m] each iter -> LDS broadcast, conflict-free
    float minsq_xy = SENTINEL;
    #pragma unroll 8
    for (int m = 0; m < MM; ++m) {
        float4 r = sR[m];
        float d0 = x.x - r.x;
        float d1 = x.y - r.y;
        float d2 = x.z - r.z;
        float d3 = x.w - r.w;
        float sq = fmaf(d0, d0, fmaf(d1, d1, fmaf(d2, d2, d3 * d3)));
        sq = sMy[m] ? sq : SENTINEL;
        minsq_xy = fminf(minsq_xy, sq);
    }

    // ---- pass 2: thread t = col m; min over valid n of squared dist ----
    float minsq_yx = SENTINEL;
    #pragma unroll 8
    for (int n = 0; n < NN; ++n) {
        float4 p = sT[n];
        float d0 = p.x - y.x;
        float d1 = p.y - y.y;
        float d2 = p.z - y.z;
        float d3 = p.w - y.w;
        float sq = fmaf(d0, d0, fmaf(d1, d1, fmaf(d2, d2, d3 * d3)));
        sq = sMx[n] ? sq : SENTINEL;
        minsq_yx = fminf(minsq_yx, sq);
    }

    // ---- per-thread contributions ----
    // min of sqrt == sqrt of min (monotone), bit-exact on the selected element
    float v_xy = mx ? sqrtf(minsq_xy) : 0.0f;                 // -> sum_xy (masked by mask_x)
    float v_yx = my ? sqrtf(minsq_yx) : 0.0f;                 // -> sum_yx (masked by mask_y)
    float normx = sqrtf(fmaf(x.x, x.x, fmaf(x.y, x.y, fmaf(x.z, x.z, x.w * x.w))));
    float normy = sqrtf(fmaf(y.x, y.x, fmaf(y.y, y.y, fmaf(y.z, y.z, y.w * y.w))));
    float v_nx  = mx ? normx : 0.0f;                          // -> sum ||x|| over nonzero pid
    float v_ny0 = my ? 0.0f : normy;                          // -> sum ||y|| over zero pid

    // ---- block reduction: wave shuffle then cross-wave via LDS ----
    #pragma unroll
    for (int off = 32; off > 0; off >>= 1) {
        v_xy  += __shfl_down(v_xy,  off, 64);
        v_yx  += __shfl_down(v_yx,  off, 64);
        v_nx  += __shfl_down(v_nx,  off, 64);
        v_ny0 += __shfl_down(v_ny0, off, 64);
    }
    const int wave = t >> 6;
    if ((t & 63) == 0) {
        wsum[wave][0] = v_xy;
        wsum[wave][1] = v_yx;
        wsum[wave][2] = v_nx;
        wsum[wave][3] = v_ny0;
    }
    __syncthreads();

    if (t == 0) {
        float s_xy = 0.f, s_yx = 0.f, s_nx = 0.f, s_ny0 = 0.f;
        #pragma unroll
        for (int w = 0; w < 4; ++w) {
            s_xy  += wsum[w][0];
            s_yx  += wsum[w][1];
            s_nx  += wsum[w][2];
            s_ny0 += wsum[w][3];
        }
        const float n_in  = (float)max(1, nx);
        const float n_out = (float)max(1, ny);
        const float normal = 0.5f * (s_xy / n_out + s_yx / n_in);
        const float eucl_nz = (ny == 0) ? (s_nx / n_in)
                                        : ((nx == 0) ? 0.0f : normal);
        const float n_zero = (float)max(1, MM - ny);
        const float eucl_z = s_ny0 / n_zero;
        atomicAdd(&out[0], eucl_nz * (1.0f / BB));
        atomicAdd(&out[1], eucl_z  * (1.0f / BB));
    }
}

extern "C" void kernel_launch(void* const* d_in, const int* in_sizes, int n_in,
                              void* d_out, int out_size, void* d_ws, size_t ws_size,
                              hipStream_t stream) {
    const float* target  = (const float*)d_in[0];
    const float* reco    = (const float*)d_in[1];
    const int*   in_pid  = (const int*)d_in[2];
    const int*   out_pid = (const int*)d_in[3];
    float* out = (float*)d_out;

    // d_out is poisoned to 0xAA before every timed launch; we accumulate via
    // atomicAdd, so zero it first (async memset is graph-capture safe).
    hipMemsetAsync(out, 0, (size_t)out_size * sizeof(float), stream);

    chamfer_split_kernel<<<dim3(BB), dim3(256), 0, stream>>>(
        target, reco, in_pid, out_pid, out);
}

// Round 2
// 74.613 us; speedup vs baseline: 1.3727x; 1.3727x over previous
//
#include <hip/hip_runtime.h>
#include <math.h>

// Problem constants (fixed by reference): B=256 batches, N=M=256 points, D=4.
#define BB 256
#define NN 256
#define MM 256

#define POISON  1.0e18f   // invalid-point coordinate: dist^2 ~ 1e36, finite, loses every min
#define MINSENT 3.0e38f

__global__ __launch_bounds__(1024) void chamfer_split_kernel(
    const float* __restrict__ target,   // [B, N, 4]
    const float* __restrict__ reco,     // [B, M, 4]
    const int*   __restrict__ in_pid,   // [B, N]
    const int*   __restrict__ out_pid,  // [B, M]
    float* __restrict__ out)            // [2] accumulated means
{
    const int b = blockIdx.x;
    const int t = threadIdx.x;   // 0..1023

    __shared__ float4 sT[NN];          // masked target points (invalid -> POISON), 4 KB
    __shared__ float4 sR[MM];          // masked reco points, 4 KB
    __shared__ float  pmin1[4][NN];    // partial row-mins (X -> R) per 64-chunk, 4 KB
    __shared__ float  pmin2[4][MM];    // partial col-mins (R -> X) per 64-chunk, 4 KB
    __shared__ int    sNx, sNy;
    __shared__ float  wsum[4][4];      // cross-wave reduction scratch (first 4 waves)

    // ---- stage batch b into LDS; only threads 0..255 (4 full waves) load ----
    float4 x = {0.f, 0.f, 0.f, 0.f};
    float4 y = {0.f, 0.f, 0.f, 0.f};
    int mx = 0, my = 0;
    if (t == 0) { sNx = 0; sNy = 0; }
    if (t < NN) {
        const float4* tg = (const float4*)(target + (size_t)b * NN * 4);
        const float4* rc = (const float4*)(reco   + (size_t)b * MM * 4);
        x = tg[t];
        y = rc[t];
        mx = (in_pid[b * NN + t] != 0);
        my = (out_pid[b * MM + t] != 0);
        float4 px = x, py = y;
        if (!mx) px = make_float4(POISON, POISON, POISON, POISON);
        if (!my) py = make_float4(POISON, POISON, POISON, POISON);
        sT[t] = px;
        sR[t] = py;
        // counts via per-wave ballot (waves 0..3 are fully active here)
        unsigned long long bx = __ballot(mx);
        unsigned long long by = __ballot(my);
        if ((t & 63) == 0) {
            atomicAdd(&sNx, (int)__popcll(bx));
            atomicAdd(&sNy, (int)__popcll(by));
        }
    }
    __syncthreads();

    // ---- concurrent passes: threads 0..511 do row-mins, 512..1023 col-mins ----
    // Each thread owns 2 rows (cols) and one 64-wide chunk of the opposite set.
    // Chunk id c = (u>>7) is wave-uniform -> inner LDS reads are broadcasts.
    if (t < 512) {
        const int c  = t >> 7;        // 0..3
        const int n0 = t & 127;
        const float4 xa = sT[n0];
        const float4 xb = sT[n0 + 128];
        float ma = MINSENT, mb = MINSENT;
        const int mbase = c << 6;
        #pragma unroll 16
        for (int i = 0; i < 64; ++i) {
            const float4 r = sR[mbase + i];
            float d0 = xa.x - r.x, d1 = xa.y - r.y, d2 = xa.z - r.z, d3 = xa.w - r.w;
            float sa = fmaf(d0, d0, fmaf(d1, d1, fmaf(d2, d2, d3 * d3)));
            ma = fminf(ma, sa);
            d0 = xb.x - r.x; d1 = xb.y - r.y; d2 = xb.z - r.z; d3 = xb.w - r.w;
            float sb = fmaf(d0, d0, fmaf(d1, d1, fmaf(d2, d2, d3 * d3)));
            mb = fminf(mb, sb);
        }
        pmin1[c][n0]       = ma;
        pmin1[c][n0 + 128] = mb;
    } else {
        const int u  = t - 512;
        const int c  = u >> 7;
        const int m0 = u & 127;
        const float4 ya = sR[m0];
        const float4 yb = sR[m0 + 128];
        float ma = MINSENT, mb = MINSENT;
        const int nbase = c << 6;
        #pragma unroll 16
        for (int i = 0; i < 64; ++i) {
            const float4 p = sT[nbase + i];
            float d0 = p.x - ya.x, d1 = p.y - ya.y, d2 = p.z - ya.z, d3 = p.w - ya.w;
            float sa = fmaf(d0, d0, fmaf(d1, d1, fmaf(d2, d2, d3 * d3)));
            ma = fminf(ma, sa);
            d0 = p.x - yb.x; d1 = p.y - yb.y; d2 = p.z - yb.z; d3 = p.w - yb.w;
            float sb = fmaf(d0, d0, fmaf(d1, d1, fmaf(d2, d2, d3 * d3)));
            mb = fminf(mb, sb);
        }
        pmin2[c][m0]       = ma;
        pmin2[c][m0 + 128] = mb;
    }
    __syncthreads();

    // ---- epilogue on threads 0..255: combine chunk mins, form contributions ----
    float v_xy = 0.f, v_yx = 0.f, v_nx = 0.f, v_ny0 = 0.f;
    if (t < NN) {
        const float mxy = fminf(fminf(pmin1[0][t], pmin1[1][t]),
                                fminf(pmin1[2][t], pmin1[3][t]));
        const float myx = fminf(fminf(pmin2[0][t], pmin2[1][t]),
                                fminf(pmin2[2][t], pmin2[3][t]));
        // min of sqrt == sqrt of min (monotone); invalid rows/cols masked below
        v_xy = mx ? sqrtf(mxy) : 0.f;
        v_yx = my ? sqrtf(myx) : 0.f;
        const float normx = sqrtf(fmaf(x.x, x.x, fmaf(x.y, x.y, fmaf(x.z, x.z, x.w * x.w))));
        const float normy = sqrtf(fmaf(y.x, y.x, fmaf(y.y, y.y, fmaf(y.z, y.z, y.w * y.w))));
        v_nx  = mx ? normx : 0.f;   // sum ||x|| over nonzero-pid targets
        v_ny0 = my ? 0.f : normy;   // sum ||y|| over zero-pid recos

        #pragma unroll
        for (int off = 32; off > 0; off >>= 1) {
            v_xy  += __shfl_down(v_xy,  off, 64);
            v_yx  += __shfl_down(v_yx,  off, 64);
            v_nx  += __shfl_down(v_nx,  off, 64);
            v_ny0 += __shfl_down(v_ny0, off, 64);
        }
        if ((t & 63) == 0) {
            const int wave = t >> 6;   // 0..3
            wsum[wave][0] = v_xy;
            wsum[wave][1] = v_yx;
            wsum[wave][2] = v_nx;
            wsum[wave][3] = v_ny0;
        }
    }
    __syncthreads();

    if (t == 0) {
        float s_xy = 0.f, s_yx = 0.f, s_nx = 0.f, s_ny0 = 0.f;
        #pragma unroll
        for (int w = 0; w < 4; ++w) {
            s_xy  += wsum[w][0];
            s_yx  += wsum[w][1];
            s_nx  += wsum[w][2];
            s_ny0 += wsum[w][3];
        }
        const int   nx    = sNx;
        const int   ny    = sNy;
        const float n_in  = (float)max(1, nx);
        const float n_out = (float)max(1, ny);
        const float normal = 0.5f * (s_xy / n_out + s_yx / n_in);
        const float eucl_nz = (ny == 0) ? (s_nx / n_in)
                                        : ((nx == 0) ? 0.0f : normal);
        const float n_zero = (float)max(1, MM - ny);
        const float eucl_z = s_ny0 / n_zero;
        atomicAdd(&out[0], eucl_nz * (1.0f / BB));
        atomicAdd(&out[1], eucl_z  * (1.0f / BB));
    }
}

extern "C" void kernel_launch(void* const* d_in, const int* in_sizes, int n_in,
                              void* d_out, int out_size, void* d_ws, size_t ws_size,
                              hipStream_t stream) {
    const float* target  = (const float*)d_in[0];
    const float* reco    = (const float*)d_in[1];
    const int*   in_pid  = (const int*)d_in[2];
    const int*   out_pid = (const int*)d_in[3];
    float* out = (float*)d_out;

    // d_out is poisoned to 0xAA before every timed launch; we accumulate via
    // atomicAdd, so zero it first (async memset is graph-capture safe).
    hipMemsetAsync(out, 0, (size_t)out_size * sizeof(float), stream);

    chamfer_split_kernel<<<dim3(BB), dim3(1024), 0, stream>>>(
        target, reco, in_pid, out_pid, out);
}

// Round 3
// 68.104 us; speedup vs baseline: 1.5039x; 1.0956x over previous
//
#include <hip/hip_runtime.h>
#include <math.h>

// Problem constants (fixed by reference): B=256 batches, N=M=256 points, D=4.
#define BB 256
#define NN 256
#define MM 256

#define POISON  1.0e18f   // invalid-point coordinate: dist^2 ~ 4e36, finite, loses every min
#define MINSENT 3.0e38f

// Kernel 1: one block per batch. 1024 threads.
//   threads   0..511 : row-mins  (each owns 8 target rows x one 16-wide reco chunk)
//   threads 512..1023: col-mins  (each owns 8 reco cols  x one 16-wide target chunk)
// Partial chunk-mins land in LDS; threads 0..255 combine, reduce, and thread 0
// writes the per-batch (eucl_nonzero, eucl_zero) pair to ws[b].
__global__ __launch_bounds__(1024) void chamfer_batch_kernel(
    const float* __restrict__ target,   // [B, N, 4]
    const float* __restrict__ reco,     // [B, M, 4]
    const int*   __restrict__ in_pid,   // [B, N]
    const int*   __restrict__ out_pid,  // [B, M]
    float2* __restrict__ ws)            // [B] per-batch results
{
    const int b = blockIdx.x;
    const int t = threadIdx.x;   // 0..1023

    __shared__ float4 sT[NN];          // masked target points (invalid -> POISON), 4 KB
    __shared__ float4 sR[MM];          // masked reco points, 4 KB
    __shared__ float  pmin1[16][NN];   // partial row-mins per 16-chunk, 16 KB
    __shared__ float  pmin2[16][MM];   // partial col-mins per 16-chunk, 16 KB
    __shared__ int    sCx[4], sCy[4];  // per-staging-wave popcounts (race-free, no atomics)
    __shared__ float  wsum[4][4];      // cross-wave reduction scratch

    // ---- stage batch b into LDS; threads 0..255 (4 full waves) load ----
    float4 x = {0.f, 0.f, 0.f, 0.f};
    float4 y = {0.f, 0.f, 0.f, 0.f};
    int mx = 0, my = 0;
    if (t < NN) {
        const float4* tg = (const float4*)(target + (size_t)b * NN * 4);
        const float4* rc = (const float4*)(reco   + (size_t)b * MM * 4);
        x = tg[t];
        y = rc[t];
        mx = (in_pid[b * NN + t] != 0);
        my = (out_pid[b * MM + t] != 0);
        float4 px = x, py = y;
        if (!mx) px = make_float4(POISON, POISON, POISON, POISON);
        if (!my) py = make_float4(POISON, POISON, POISON, POISON);
        sT[t] = px;
        sR[t] = py;
        unsigned long long bx = __ballot(mx);
        unsigned long long by = __ballot(my);
        if ((t & 63) == 0) {
            sCx[t >> 6] = (int)__popcll(bx);
            sCy[t >> 6] = (int)__popcll(by);
        }
    }
    __syncthreads();

    // ---- concurrent passes, 8-way register tiling ----
    // u = thread slot within a pass (0..511): chunk c = u>>5 (16-wide slice of the
    // "other" set), row-group g = u&31 -> rows g, g+32, ..., g+224.
    // Inner LDS reads use 2 distinct addresses per wave (c spans 2 values) ->
    // 2-way aliasing, which is free on gfx950.
    {
        const bool pass1 = (t < 512);
        const int  u = pass1 ? t : (t - 512);
        const int  c = u >> 5;        // 0..15
        const int  g = u & 31;
        const float4* own   = pass1 ? sT : sR;   // points whose mins we track
        const float4* other = pass1 ? sR : sT;   // points we scan
        float (*pout)[256]  = pass1 ? pmin1 : pmin2;

        float4 p0 = own[g];
        float4 p1 = own[g + 32];
        float4 p2 = own[g + 64];
        float4 p3 = own[g + 96];
        float4 p4 = own[g + 128];
        float4 p5 = own[g + 160];
        float4 p6 = own[g + 192];
        float4 p7 = own[g + 224];
        float m0 = MINSENT, m1 = MINSENT, m2 = MINSENT, m3 = MINSENT;
        float m4 = MINSENT, m5 = MINSENT, m6 = MINSENT, m7 = MINSENT;
        const int base = c << 4;
        #pragma unroll 4
        for (int i = 0; i < 16; ++i) {
            const float4 r = other[base + i];
            float d0, d1, d2, d3, sq;
            d0 = p0.x - r.x; d1 = p0.y - r.y; d2 = p0.z - r.z; d3 = p0.w - r.w;
            sq = fmaf(d0, d0, fmaf(d1, d1, fmaf(d2, d2, d3 * d3))); m0 = fminf(m0, sq);
            d0 = p1.x - r.x; d1 = p1.y - r.y; d2 = p1.z - r.z; d3 = p1.w - r.w;
            sq = fmaf(d0, d0, fmaf(d1, d1, fmaf(d2, d2, d3 * d3))); m1 = fminf(m1, sq);
            d0 = p2.x - r.x; d1 = p2.y - r.y; d2 = p2.z - r.z; d3 = p2.w - r.w;
            sq = fmaf(d0, d0, fmaf(d1, d1, fmaf(d2, d2, d3 * d3))); m2 = fminf(m2, sq);
            d0 = p3.x - r.x; d1 = p3.y - r.y; d2 = p3.z - r.z; d3 = p3.w - r.w;
            sq = fmaf(d0, d0, fmaf(d1, d1, fmaf(d2, d2, d3 * d3))); m3 = fminf(m3, sq);
            d0 = p4.x - r.x; d1 = p4.y - r.y; d2 = p4.z - r.z; d3 = p4.w - r.w;
            sq = fmaf(d0, d0, fmaf(d1, d1, fmaf(d2, d2, d3 * d3))); m4 = fminf(m4, sq);
            d0 = p5.x - r.x; d1 = p5.y - r.y; d2 = p5.z - r.z; d3 = p5.w - r.w;
            sq = fmaf(d0, d0, fmaf(d1, d1, fmaf(d2, d2, d3 * d3))); m5 = fminf(m5, sq);
            d0 = p6.x - r.x; d1 = p6.y - r.y; d2 = p6.z - r.z; d3 = p6.w - r.w;
            sq = fmaf(d0, d0, fmaf(d1, d1, fmaf(d2, d2, d3 * d3))); m6 = fminf(m6, sq);
            d0 = p7.x - r.x; d1 = p7.y - r.y; d2 = p7.z - r.z; d3 = p7.w - r.w;
            sq = fmaf(d0, d0, fmaf(d1, d1, fmaf(d2, d2, d3 * d3))); m7 = fminf(m7, sq);
        }
        // [c][row] layout: lane banks = row%32 -> 2-way aliasing across half-waves, free
        pout[c][g]       = m0;
        pout[c][g + 32]  = m1;
        pout[c][g + 64]  = m2;
        pout[c][g + 96]  = m3;
        pout[c][g + 128] = m4;
        pout[c][g + 160] = m5;
        pout[c][g + 192] = m6;
        pout[c][g + 224] = m7;
    }
    __syncthreads();

    // ---- epilogue on threads 0..255: combine 16 chunk-mins per row/col ----
    float v_xy = 0.f, v_yx = 0.f, v_nx = 0.f, v_ny0 = 0.f;
    if (t < NN) {
        float mxy = pmin1[0][t];
        float myx = pmin2[0][t];
        #pragma unroll
        for (int c = 1; c < 16; ++c) {
            mxy = fminf(mxy, pmin1[c][t]);
            myx = fminf(myx, pmin2[c][t]);
        }
        // min of sqrt == sqrt of min (monotone); invalid rows/cols masked below
        v_xy = mx ? sqrtf(mxy) : 0.f;
        v_yx = my ? sqrtf(myx) : 0.f;
        const float normx = sqrtf(fmaf(x.x, x.x, fmaf(x.y, x.y, fmaf(x.z, x.z, x.w * x.w))));
        const float normy = sqrtf(fmaf(y.x, y.x, fmaf(y.y, y.y, fmaf(y.z, y.z, y.w * y.w))));
        v_nx  = mx ? normx : 0.f;   // sum ||x|| over nonzero-pid targets
        v_ny0 = my ? 0.f : normy;   // sum ||y|| over zero-pid recos

        #pragma unroll
        for (int off = 32; off > 0; off >>= 1) {
            v_xy  += __shfl_down(v_xy,  off, 64);
            v_yx  += __shfl_down(v_yx,  off, 64);
            v_nx  += __shfl_down(v_nx,  off, 64);
            v_ny0 += __shfl_down(v_ny0, off, 64);
        }
        if ((t & 63) == 0) {
            const int wave = t >> 6;   // 0..3
            wsum[wave][0] = v_xy;
            wsum[wave][1] = v_yx;
            wsum[wave][2] = v_nx;
            wsum[wave][3] = v_ny0;
        }
    }
    __syncthreads();

    if (t == 0) {
        float s_xy = 0.f, s_yx = 0.f, s_nx = 0.f, s_ny0 = 0.f;
        int nx = 0, ny = 0;
        #pragma unroll
        for (int w = 0; w < 4; ++w) {
            s_xy  += wsum[w][0];
            s_yx  += wsum[w][1];
            s_nx  += wsum[w][2];
            s_ny0 += wsum[w][3];
            nx    += sCx[w];
            ny    += sCy[w];
        }
        const float n_in  = (float)max(1, nx);
        const float n_out = (float)max(1, ny);
        const float normal = 0.5f * (s_xy / n_out + s_yx / n_in);
        const float eucl_nz = (ny == 0) ? (s_nx / n_in)
                                        : ((nx == 0) ? 0.0f : normal);
        const float n_zero = (float)max(1, MM - ny);
        const float eucl_z = s_ny0 / n_zero;
        ws[b] = make_float2(eucl_nz, eucl_z);
    }
}

// Kernel 2: single block reduces the 256 per-batch pairs and writes the two
// output means with plain stores (no atomics -> no output memset needed).
__global__ __launch_bounds__(256) void chamfer_final_kernel(
    const float2* __restrict__ ws, float* __restrict__ out)
{
    const int t = threadIdx.x;   // 0..255
    __shared__ float2 s[4];
    float2 v = ws[t];
    #pragma unroll
    for (int off = 32; off > 0; off >>= 1) {
        v.x += __shfl_down(v.x, off, 64);
        v.y += __shfl_down(v.y, off, 64);
    }
    if ((t & 63) == 0) s[t >> 6] = v;
    __syncthreads();
    if (t == 0) {
        float a = 0.f, bsum = 0.f;
        #pragma unroll
        for (int w = 0; w < 4; ++w) { a += s[w].x; bsum += s[w].y; }
        out[0] = a * (1.0f / BB);
        out[1] = bsum * (1.0f / BB);
    }
}

extern "C" void kernel_launch(void* const* d_in, const int* in_sizes, int n_in,
                              void* d_out, int out_size, void* d_ws, size_t ws_size,
                              hipStream_t stream) {
    const float* target  = (const float*)d_in[0];
    const float* reco    = (const float*)d_in[1];
    const int*   in_pid  = (const int*)d_in[2];
    const int*   out_pid = (const int*)d_in[3];
    float* out = (float*)d_out;
    float2* ws = (float2*)d_ws;

    chamfer_batch_kernel<<<dim3(BB), dim3(1024), 0, stream>>>(
        target, reco, in_pid, out_pid, ws);
    chamfer_final_kernel<<<dim3(1), dim3(256), 0, stream>>>(ws, out);
}